// Round 10
// baseline (386.418 us; speedup 1.0000x reference)
//
#include <hip/hip_runtime.h>
#include <hip/hip_fp16.h>
#include <stdint.h>

#define V_N   50257
#define NPAN  393                    // ceil(V_N/128)
#define NCH   1024
#define MT    4096                   // B*S
#define KC    512                    // 2*N_FREQ
#define NFRQ  256
#define TWO_PI 6.28318530717958647692f

typedef _Float16 f16;
typedef __attribute__((ext_vector_type(8))) _Float16 f16x8;
typedef __attribute__((ext_vector_type(4))) float    f32x4;

#define CFENCE asm volatile("" ::: "memory")

// ---------------- Kernel 1: Y = h @ w, stored PRE-SWIZZLED in MFMA fragment order ----
// A_ws index: ((r16*8 + kt)*2 + ks)*512 + lg*128 + lr*8 + e
//   r16 = row>>4, lr = row&15, kt = col>>6, q = col&63, ks = q>>5, lg = (q>>3)&3, e = q&7
// so k2 can load fragments with lane-contiguous global_load_dwordx4 (addr = base + lane*8).
__global__ __launch_bounds__(256) void k1_proj(
    const float* __restrict__ h, const float* __restrict__ w, f16* __restrict__ A) {
  __shared__ __align__(16) f16 As[64 * 64];
  __shared__ __align__(16) f16 Bs[64 * 64];
  const int tid = threadIdx.x;
  const int bn0 = blockIdx.x * 64;
  const int bm0 = blockIdx.y * 64;
  const int lane = tid & 63, wid = tid >> 6;
  const int lr = lane & 15, lg = lane >> 4;
  const int wr = wid >> 1, wc = wid & 1;

  f32x4 acc[2][2];
#pragma unroll
  for (int i = 0; i < 2; ++i)
#pragma unroll
    for (int j = 0; j < 2; ++j) acc[i][j] = (f32x4){0.f, 0.f, 0.f, 0.f};

  for (int s = 0; s < NCH / 64; ++s) {
    const int k0 = s * 64;
    __syncthreads();
#pragma unroll
    for (int r = 0; r < 2; ++r) {
      int q = tid + r * 256;
      int m = q >> 3, c = q & 7;
      const float* src = h + (size_t)(bm0 + m) * NCH + k0 + c * 8;
      f32x4 v0 = *(const f32x4*)src;
      f32x4 v1 = *(const f32x4*)(src + 4);
      f16x8 pk;
#pragma unroll
      for (int e = 0; e < 4; ++e) { pk[e] = (f16)v0[e]; pk[4 + e] = (f16)v1[e]; }
      *(f16x8*)&As[m * 64 + ((c ^ (m & 7)) << 3)] = pk;
    }
#pragma unroll
    for (int r = 0; r < 2; ++r) {
      int q = tid + r * 256;
      int c = q >> 6, n = q & 63;
      int jj = bn0 + n;
      int wcol = (jj >> 1) + ((jj & 1) ? NFRQ : 0);
      f16x8 pk;
#pragma unroll
      for (int j = 0; j < 8; ++j)
        pk[j] = (f16)w[(size_t)(k0 + c * 8 + j) * KC + wcol];
      *(f16x8*)&Bs[n * 64 + ((c ^ (n & 7)) << 3)] = pk;
    }
    __syncthreads();
#pragma unroll
    for (int kk = 0; kk < 2; ++kk) {
      const int cb = kk * 4 + lg;
      f16x8 a[2], b[2];
#pragma unroll
      for (int mi = 0; mi < 2; ++mi) {
        int row = wr * 32 + mi * 16 + lr;
        a[mi] = *(const f16x8*)&As[row * 64 + ((cb ^ (row & 7)) << 3)];
      }
#pragma unroll
      for (int ni = 0; ni < 2; ++ni) {
        int col = wc * 32 + ni * 16 + lr;
        b[ni] = *(const f16x8*)&Bs[col * 64 + ((cb ^ (col & 7)) << 3)];
      }
#pragma unroll
      for (int mi = 0; mi < 2; ++mi)
#pragma unroll
        for (int ni = 0; ni < 2; ++ni)
          acc[mi][ni] = __builtin_amdgcn_mfma_f32_16x16x32_f16(a[mi], b[ni], acc[mi][ni], 0, 0, 0);
    }
  }
  // epilogue: scatter into fragment-order layout
#pragma unroll
  for (int mi = 0; mi < 2; ++mi)
#pragma unroll
    for (int ni = 0; ni < 2; ++ni)
#pragma unroll
      for (int r = 0; r < 4; ++r) {
        int row = bm0 + wr * 32 + mi * 16 + lg * 4 + r;
        int col = bn0 + wc * 32 + ni * 16 + lr;
        int r16 = row >> 4, lrA = row & 15;
        int kt = col >> 6, q = col & 63;
        int ks = q >> 5, lgA = (q >> 3) & 3, e = q & 7;
        size_t off = ((((size_t)r16 * 8 + kt) * 2 + ks) * 4 + lgA) * 128 + lrA * 8 + e;
        A[off] = (f16)acc[mi][ni][r];
      }
}

// ---------------- Kernel 2: A in REGISTERS (frag-order gloads), B single-buffer LDS --
// 128x128 tile, 4 waves, BK=64. A: frag-order global_load_dwordx4, reg double-buffer,
// compiler-counted vmcnt. B: exact-seeded OTF gen into regs, write-after-read single
// LDS buffer (16 KB). Raw s_barrier + lgkmcnt(0) only (no vmcnt drain at barriers).

__device__ __forceinline__ void load_a(const f16* __restrict__ A, int bm0, int wr,
                                       int kt, int lane, f16x8 a[4][2]) {
  const int r16b = (bm0 >> 4) + wr * 4;
#pragma unroll
  for (int mi = 0; mi < 4; ++mi)
#pragma unroll
    for (int ks = 0; ks < 2; ++ks) {
      size_t off = (((size_t)(r16b + mi) * 8 + kt) * 2 + ks) * 512 + (size_t)lane * 8;
      a[mi][ks] = *(const f16x8*)&A[off];
    }
}

__device__ __forceinline__ void compute_reg(
    const f16x8 a[4][2], const f16* __restrict__ CB,
    int wr, int wc, int lr, int lg, f32x4 acc[4][4]) {
#pragma unroll
  for (int ks = 0; ks < 2; ++ks) {
    const int cb = ks * 4 + lg;
    f16x8 b[4];
#pragma unroll
    for (int ni = 0; ni < 4; ++ni) {
      int col = wc * 64 + ni * 16 + lr;
      b[ni] = *(const f16x8*)&CB[col * 64 + ((cb ^ (col & 7)) << 3)];
    }
    __builtin_amdgcn_s_setprio(1);
#pragma unroll
    for (int mi = 0; mi < 4; ++mi)
#pragma unroll
      for (int ni = 0; ni < 4; ++ni)
        acc[mi][ni] = __builtin_amdgcn_mfma_f32_16x16x32_f16(a[mi][ks], b[ni], acc[mi][ni], 0, 0, 0);
    __builtin_amdgcn_s_setprio(0);
  }
}

// base = e^{i*w0*((32s+16g)*t mod V)} — exact integer reduction, no chaining
__device__ __forceinline__ void seed_base(int s, int g, int t, float& br, float& bi) {
  int fb = 32 * s + 16 * g;
  int m = (fb * t) % V_N;
  float sn, cs;
  __sincosf((TWO_PI / (float)V_N) * (float)m, &sn, &cs);
  br = cs; bi = sn;
}

__device__ __forceinline__ void gen_bt(const float Tr[16], const float Ti[16],
                                       float br, float bi, f16x8 bt[4]) {
#pragma unroll
  for (int u = 0; u < 4; ++u)
#pragma unroll
    for (int p = 0; p < 4; ++p) {
      const int j = 4 * u + p;
      float re = br * Tr[j] - bi * Ti[j];
      float im = br * Ti[j] + bi * Tr[j];
      bt[u][2 * p]     = (f16)re;
      bt[u][2 * p + 1] = (f16)(-im);
    }
}

__device__ __forceinline__ void store_bt(f16* Bs, int nloc, int g, const f16x8 bt[4]) {
#pragma unroll
  for (int u = 0; u < 4; ++u) {
    int c = 4 * g + u;
    *(f16x8*)&Bs[nloc * 64 + ((c ^ (nloc & 7)) << 3)] = bt[u];
  }
}

#define K2_TILE(S, AC, AN)                                                \
  do {                                                                    \
    enum { s_ = (S) };                                                    \
    if (s_ < 7) {                                                         \
      load_a(A, bm0, wr, s_ + 1, lane, AN);                               \
      float br_, bi_;                                                     \
      seed_base(s_ + 1, g, t, br_, bi_);                                  \
      gen_bt(Tr, Ti, br_, bi_, btn);                                      \
    }                                                                     \
    CFENCE;                                                               \
    asm volatile("s_waitcnt lgkmcnt(0)" ::: "memory");                    \
    __builtin_amdgcn_s_barrier();                                         \
    compute_reg(AC, Bs, wr, wc, lr, lg, acc);                             \
    CFENCE;                                                               \
    __builtin_amdgcn_s_barrier();                                         \
    if (s_ < 7) store_bt(Bs, nloc, g, btn);                               \
  } while (0)

__global__ __launch_bounds__(256, 2) void k2_areg(
    const f16* __restrict__ A, float* __restrict__ out) {
  __shared__ __align__(16) f16 Bs[128 * 64];     // only B in LDS: 16 KB
  const int tid = threadIdx.x;
  // XCD bijective swizzle (12576 = 8*1572), by-MAJOR: XCD x owns by in {4x..4x+3}
  // -> its A slice (512 KB frag-order) is L2-resident; adjacent bx co-resident.
  const int orig = blockIdx.x;
  const int wgid = (orig & 7) * 1572 + (orig >> 3);
  const int by = wgid / 393;
  const int bx = wgid - by * 393;
  const int bn0 = bx << 7;
  const int bm0 = by << 7;
  const int lane = tid & 63, wid = tid >> 6;
  const int lr = lane & 15, lg = lane >> 4;
  const int wr = wid >> 1, wc = wid & 1;

  // ---- B-gen init: T[j] = e^{i*w0*((j+1)t mod V)}, exact-seeded ----
  const int nloc = tid & 127;
  const int g = tid >> 7;
  int t = bn0 + nloc;
  if (t >= V_N) t -= V_N;                        // tail cols alias; never written
  const float w0 = TWO_PI / (float)V_N;
  float Tr[16], Ti[16];
#pragma unroll
  for (int j = 0; j < 16; ++j) {
    int m = ((j + 1) * t) % V_N;
    float sn, cs;
    __sincosf(w0 * (float)m, &sn, &cs);
    Tr[j] = cs; Ti[j] = sn;
  }

  f32x4 acc[4][4];
#pragma unroll
  for (int i = 0; i < 4; ++i)
#pragma unroll
    for (int j = 0; j < 4; ++j) acc[i][j] = (f32x4){0.f, 0.f, 0.f, 0.f};

  // ---- prologue: B(0) -> Bs, A(0) -> regs ----
  {
    float br, bi;
    seed_base(0, g, t, br, bi);
    f16x8 bt[4];
    gen_bt(Tr, Ti, br, bi, bt);
    store_bt(Bs, nloc, g, bt);
  }
  f16x8 aA[4][2], aB[4][2], btn[4];
  load_a(A, bm0, wr, 0, lane, aA);

  K2_TILE(0, aA, aB);
  K2_TILE(1, aB, aA);
  K2_TILE(2, aA, aB);
  K2_TILE(3, aB, aA);
  K2_TILE(4, aA, aB);
  K2_TILE(5, aB, aA);
  K2_TILE(6, aA, aB);
  K2_TILE(7, aB, aA);

  const float scale = 2.0f / (float)V_N;
#pragma unroll
  for (int ni = 0; ni < 4; ++ni) {
    int col = bn0 + wc * 64 + ni * 16 + lr;
    if (col < V_N) {
#pragma unroll
      for (int mi = 0; mi < 4; ++mi)
#pragma unroll
        for (int r = 0; r < 4; ++r) {
          int row = bm0 + wr * 64 + mi * 16 + lg * 4 + r;
          out[(size_t)row * V_N + col] = acc[mi][ni][r] * scale;
        }
    }
  }
}

extern "C" void kernel_launch(void* const* d_in, const int* in_sizes, int n_in,
                              void* d_out, int out_size, void* d_ws, size_t ws_size,
                              hipStream_t stream) {
  const float* h = (const float*)d_in[0];
  const float* w = (const float*)d_in[1];
  float* out = (float*)d_out;
  f16* A = (f16*)d_ws;                           // MT*KC*2 = 4.2 MB scratch

  dim3 blk(256);
  hipLaunchKernelGGL(k1_proj, dim3(KC / 64, MT / 64), blk, 0, stream, h, w, A);
  hipLaunchKernelGGL(k2_areg, dim3(NPAN * 32), blk, 0, stream, A, out);
}